// Round 22
// baseline (242.575 us; speedup 1.0000x reference)
//
#include <hip/hip_runtime.h>

#define HIDN 128
#define VSTR 272           // LDS V-buffer row stride BYTES (17x16B -> conflict-free b128)
#define ASTR 132           // f32 activation row stride (floats)

// d_ws byte offsets. Forward weights TRANSPOSED: WT[jc][unit][4kk] f32, row
// stride 2064B (non-pow2 — R14). Per jc the 32 needed units are 512B contiguous.
#define WSB_W2T 0                    // f32 [32][128][4], rows 2064B
#define WSB_W3T 66048
#define WSB_W2B 135168               // bf16 [128] rows, stride 272B (tangent)
#define WSB_W3B 169984
#define WSB_W4B 204800               // bf16 [16] rows, stride 272B (rows 4..15 zero)
#define WSB_W1T 209152               // bf16 [4][128] contiguous
#define WSB_TOT 210176

typedef __attribute__((ext_vector_type(8))) short short8;
typedef __attribute__((ext_vector_type(4))) float f32x4;

// Paired-row bf16 W load: 8 loads + wait in ONE self-contained asm block
// (R13-proven; multi-block register pipelines spill — R16, 3-for-3).
#define LOAD_A8(dst, b0, b1)                                                  \
    asm volatile("global_load_dwordx4 %0, %8, off\n\t"                        \
                 "global_load_dwordx4 %1, %8, off offset:64\n\t"              \
                 "global_load_dwordx4 %2, %8, off offset:128\n\t"             \
                 "global_load_dwordx4 %3, %8, off offset:192\n\t"             \
                 "global_load_dwordx4 %4, %9, off\n\t"                        \
                 "global_load_dwordx4 %5, %9, off offset:64\n\t"              \
                 "global_load_dwordx4 %6, %9, off offset:128\n\t"             \
                 "global_load_dwordx4 %7, %9, off offset:192\n\t"             \
                 "s_waitcnt vmcnt(0)"                                         \
                 : "=&v"(dst[0]), "=&v"(dst[1]), "=&v"(dst[2]), "=&v"(dst[3]),\
                   "=&v"(dst[4]), "=&v"(dst[5]), "=&v"(dst[6]), "=&v"(dst[7]) \
                 : "v"(b0), "v"(b1)                                           \
                 : "memory")

// f32 -> bf16 round-to-nearest-even
__device__ __forceinline__ unsigned short f2bf(float f) {
    unsigned b = __float_as_uint(f);
    b += 0x7FFFu + ((b >> 16) & 1u);
    return (unsigned short)(b >> 16);
}

// ---------- prelude: one-time weight repack into ws ----------
__global__ void conv_w_kernel(const float* __restrict__ W1, const float* __restrict__ W2,
                              const float* __restrict__ W3, const float* __restrict__ W4,
                              unsigned char* __restrict__ ws)
{
    const int idx = blockIdx.x * 256 + threadIdx.x;
    if (idx < 16384) {
        const int r = idx >> 7, c = idx & 127;           // unit r, k-col c
        const int jc = c >> 2, kk = c & 3;
        *(float*)(ws + WSB_W2T + jc * 2064 + r * 16 + kk * 4) = W2[idx];   // f32 verbatim
        *(float*)(ws + WSB_W3T + jc * 2064 + r * 16 + kk * 4) = W3[idx];
        *(unsigned short*)(ws + WSB_W2B + r * 272 + c * 2) = f2bf(W2[idx]);
        *(unsigned short*)(ws + WSB_W3B + r * 272 + c * 2) = f2bf(W3[idx]);
    } else if (idx < 16384 + 2048) {
        const int t = idx - 16384;
        const int r = t >> 7, c = t & 127;
        *(unsigned short*)(ws + WSB_W4B + r * 272 + c * 2) =
            (r < 4) ? f2bf(W4[r * HIDN + c]) : (unsigned short)0;
    } else if (idx < 16384 + 2048 + 512) {
        const int t = idx - 16384 - 2048;
        const int cc = t >> 7, j = t & 127;
        *(unsigned short*)(ws + WSB_W1T + cc * 256 + j * 2) = f2bf(W1[j * 4 + cc]);
    }
}

// One tangent layer, WIDE split (R21-proven): wave owns UNITS [ub, ub+32) for
// ALL 64 sc-rows. W fragments aw[8] are REGISTER-RESIDENT (hoisted, R22).
// PING-PONG src != dst (in-place corrupts — R6/R8). msk = SUBTILE SAMPLE BASE.
__device__ __forceinline__ void tangent_layer_wide(const unsigned char* __restrict__ src,
                                                   unsigned char* __restrict__ dst,
                                                   const short8* __restrict__ aw,      // [8] regs
                                                   const unsigned char* __restrict__ msk, // [16][16]
                                                   int ib0, int lr, int lk)
{
    #pragma unroll
    for (int q = 0; q < 4; ++q) {
        const int sc = q * 16 + lr;
        short8 b[4];
        #pragma unroll
        for (int ks = 0; ks < 4; ++ks)
            b[ks] = *(const short8*)(src + sc * VSTR + ks * 64 + lk * 16);
        #pragma unroll
        for (int h = 0; h < 2; ++h) {
            const int ib = ib0 + h;
            f32x4 c = (f32x4){0.f, 0.f, 0.f, 0.f};
            #pragma unroll
            for (int ks = 0; ks < 4; ++ks)
                c = __builtin_amdgcn_mfma_f32_16x16x32_bf16(aw[h * 4 + ks], b[ks], c, 0, 0, 0);
            const unsigned bits = (msk[(sc >> 2) * 16 + ib * 2 + (lk >> 1)] >> ((lk & 1) * 4)) & 0xFu;
            unsigned long long pk = 0;
            #pragma unroll
            for (int r = 0; r < 4; ++r) {
                const unsigned short v = ((bits >> r) & 1u) ? f2bf(c[r]) : (unsigned short)0;
                pk |= (unsigned long long)v << (r * 16);
            }
            *(unsigned long long*)(dst + sc * VSTR + (ib * 16 + lk * 4) * 2) = pk;
        }
    }
}

__global__ __launch_bounds__(256, 4)
void wnn_jac_kernel(const float* __restrict__ u,
                    const float* __restrict__ W1, const float* __restrict__ b1,
                    const float* __restrict__ b2, const float* __restrict__ b3,
                    const unsigned char* __restrict__ wsb,
                    float* __restrict__ out, int Btot)
{
    // [0,17408) vA ; [17408,34816) vB ; forward aliases [0,33792) as f32 abuf[64][132]
    __shared__ __align__(16) unsigned char smem[34816];
    __shared__ unsigned char mlds8[3][64][16];   // [layer][sample][unit>>3] (3072 B)
    __shared__ float jbuf[64 * 5];               // [sc][c'] stride 5 (1280 B)

    unsigned char* vA = smem;
    unsigned char* vB = smem + 17408;
    float* abuf = (float*)smem;

    const int tid  = threadIdx.x;
    const long sg0 = (long)blockIdx.x * 64;

    // ================== FORWARD: lane = sample, wave = unit-quarter (uniform W) — R20 verbatim ==================
    {
        const int ls = tid & 63;                                   // sample
        const int wq = __builtin_amdgcn_readfirstlane(tid >> 6);   // uniform quarter 0..3
        const int i0 = wq * 32;
        const bool valid = (sg0 + ls < (long)Btot);

        float4 uv = make_float4(0.f, 0.f, 0.f, 0.f);
        if (valid) uv = *(const float4*)(u + (sg0 + ls) * 4);

        // ---- layer 1: 32 units/wave (uniform W1 rows), bit-exact chain, bias after ----
        {
            unsigned m = 0;
            #pragma unroll
            for (int ii = 0; ii < 32; ++ii) {
                const int i = i0 + ii;
                const float4 w = *(const float4*)(W1 + i * 4);     // uniform
                float h = 0.f;
                h = fmaf(w.x, uv.x, h);
                h = fmaf(w.y, uv.y, h);
                h = fmaf(w.z, uv.z, h);
                h = fmaf(w.w, uv.w, h);
                h = h + b1[i];
                if (h > 0.f) m |= (1u << ii);
                abuf[ls * ASTR + i] = fmaxf(h, 0.f);
            }
            *(unsigned*)&mlds8[0][ls][wq * 4] = m;
        }
        __syncthreads();   // B1: a1 complete

        // ---- layer 2: jc-OUTER / all-32-units-INNER (R20-proven) ----
        float acc2[32];
        {
            #pragma unroll
            for (int ii = 0; ii < 32; ++ii) acc2[ii] = 0.f;
            #pragma unroll 8
            for (int jc = 0; jc < 32; ++jc) {
                const f32x4 av = *(const f32x4*)(abuf + ls * ASTR + jc * 4);
                const float* wt = (const float*)(wsb + WSB_W2T + jc * 2064 + i0 * 16); // uniform 512B
                #pragma unroll
                for (int ii = 0; ii < 32; ++ii) {
                    const float* wr = wt + ii * 4;
                    float a = acc2[ii];
                    a = fmaf(wr[0], av[0], a);
                    a = fmaf(wr[1], av[1], a);
                    a = fmaf(wr[2], av[2], a);
                    a = fmaf(wr[3], av[3], a);
                    acc2[ii] = a;
                }
            }
        }
        __syncthreads();   // B2: ALL a1 reads complete -> safe to overwrite abuf with a2
        {
            unsigned m = 0;
            #pragma unroll
            for (int ii = 0; ii < 32; ++ii) {
                const float h = acc2[ii] + b2[i0 + ii];
                if (h > 0.f) m |= (1u << ii);
                abuf[ls * ASTR + i0 + ii] = fmaxf(h, 0.f);
            }
            *(unsigned*)&mlds8[1][ls][wq * 4] = m;
        }
        __syncthreads();   // B3: a2 complete

        // ---- layer 3 (mask only), same jc-outer structure ----
        {
            #pragma unroll
            for (int ii = 0; ii < 32; ++ii) acc2[ii] = 0.f;
            #pragma unroll 8
            for (int jc = 0; jc < 32; ++jc) {
                const f32x4 av = *(const f32x4*)(abuf + ls * ASTR + jc * 4);
                const float* wt = (const float*)(wsb + WSB_W3T + jc * 2064 + i0 * 16); // uniform 512B
                #pragma unroll
                for (int ii = 0; ii < 32; ++ii) {
                    const float* wr = wt + ii * 4;
                    float a = acc2[ii];
                    a = fmaf(wr[0], av[0], a);
                    a = fmaf(wr[1], av[1], a);
                    a = fmaf(wr[2], av[2], a);
                    a = fmaf(wr[3], av[3], a);
                    acc2[ii] = a;
                }
            }
            unsigned m = 0;
            #pragma unroll
            for (int ii = 0; ii < 32; ++ii) {
                const float h = acc2[ii] + b3[i0 + ii];
                if (h > 0.f) m |= (1u << ii);
            }
            *(unsigned*)&mlds8[2][ls][wq * 4] = m;
        }
    }
    __syncthreads();   // B4: masks visible; abuf dead -> vA/vB reusable

    // ================== TANGENT: 4 subtiles, wide unit-split, reg-resident W (R22) ==================
    const unsigned char* ml8 = &mlds8[0][0][0];
    const int lane = tid & 63, wv = tid >> 6;
    const int lr = lane & 15, lk = lane >> 4;
    const int ub = wv * 32;    // this wave's unit base for tangent layers
    const int ib0 = ub >> 4;

    // ---- hoist ALL subtile-invariant W fragments into registers (R22) ----
    short8 aw2[8], aw3[8];
    LOAD_A8(aw2, wsb + WSB_W2B + (ub + lr) * 272 + lk * 16,
                 wsb + WSB_W2B + (ub + 16 + lr) * 272 + lk * 16);
    LOAD_A8(aw3, wsb + WSB_W3B + (ub + lr) * 272 + lk * 16,
                 wsb + WSB_W3B + (ub + 16 + lr) * 272 + lk * 16);
    short8 a4f[4];
    #pragma unroll
    for (int ks = 0; ks < 4; ++ks)
        a4f[ks] = *(const short8*)(wsb + WSB_W4B + lr * 272 + ks * 64 + lk * 16);
    short8 w1v[4];   // v1-build W1 column fragments (vc = (lane>>2)&3, kq = lane&3)
    {
        const int kq = lane & 3, vc = (lane >> 2) & 3;
        const unsigned short* w1t = (const unsigned short*)(wsb + WSB_W1T) + vc * HIDN;
        #pragma unroll
        for (int t = 0; t < 4; ++t)
            w1v[t] = *(const short8*)(w1t + kq * 32 + t * 8);
    }

    #pragma unroll 1
    for (int st = 0; st < 4; ++st) {
        __syncthreads();   // prev subtile's vA readers (Jf/L3 writers) done -> v1 may overwrite

        // ---- v1 build: vA rows [wv*16, wv*16+16) = bf16(m1 .* W1 cols), reg W ----
        {
            const int row = wv * 16 + (lane >> 2), kq = lane & 3;
            const int vs = (lane >> 4);
            const unsigned char* mrec = ml8 + (0 * 64 + st * 16 + wv * 4 + vs) * 16;
            #pragma unroll
            for (int t = 0; t < 4; ++t) {
                const int j0 = kq * 32 + t * 8;
                const short8 w = w1v[t];
                short8 fr;
                #pragma unroll
                for (int e = 0; e < 8; ++e) {
                    const int j = j0 + e;
                    fr[e] = ((mrec[j >> 3] >> (j & 7)) & 1u) ? w[e] : (short)0;
                }
                *(short8*)(vA + row * VSTR + j0 * 2) = fr;
            }
        }
        __syncthreads();   // all vA rows ready (L2 reads every row)

        // ---- tangent L2: vA -> vB (reg-resident aw2) ----
        tangent_layer_wide(vA, vB, aw2, ml8 + (1 * 64 + st * 16) * 16, ib0, lr, lk);
        __syncthreads();   // all vB writes visible

        // ---- tangent L3: vB -> vA (reg-resident aw3) ----
        tangent_layer_wide(vB, vA, aw3, ml8 + (2 * 64 + st * 16) * 16, ib0, lr, lk);
        __syncthreads();   // all vA writes visible (Jf reads full rows)

        // ---- Jf: D[c'][sc] = sum_j W4[c'][j] * V3[sc][j] (own wave's 16 rows) ----
        {
            short8 b[4];
            #pragma unroll
            for (int ks = 0; ks < 4; ++ks)
                b[ks] = *(const short8*)(vA + (wv * 16 + lr) * VSTR + ks * 64 + lk * 16);
            f32x4 c = (f32x4){0.f, 0.f, 0.f, 0.f};
            #pragma unroll
            for (int ks = 0; ks < 4; ++ks)
                c = __builtin_amdgcn_mfma_f32_16x16x32_bf16(a4f[ks], b[ks], c, 0, 0, 0);
            if (lk == 0) {   // c' = r (0..3); sc = wv*16+lr -> jbuf rows wave-private
                const int sc = wv * 16 + lr;
                #pragma unroll
                for (int r = 0; r < 4; ++r)
                    jbuf[sc * 5 + r] = c[r];
            }
        }
        // wave-internal jbuf handoff: both sides are LDS ops -> "memory" clobber orders them
        asm volatile("s_waitcnt lgkmcnt(0)" ::: "memory");
        __builtin_amdgcn_sched_barrier(0);

        // ---- per-wave epilogue (lanes 0-15): samples wv*4 .. wv*4+3 of this subtile ----
        if (lk == 0) {
            const int es = lr >> 2, ea = lr & 3;
            const long sg = sg0 + st * 16 + wv * 4 + es;
            if (sg < (long)Btot) {
                const float* jb = jbuf + (wv * 16 + es * 4) * 5;
                float4 o;
                o.x = jb[ea * 5 + 0] - jb[0 * 5 + ea];
                o.y = jb[ea * 5 + 1] - jb[1 * 5 + ea];
                o.z = jb[ea * 5 + 2] - jb[2 * 5 + ea];
                o.w = jb[ea * 5 + 3] - jb[3 * 5 + ea];
                *(float4*)(out + sg * 16 + ea * 4) = o;
            }
        }
    }
}

extern "C" void kernel_launch(void* const* d_in, const int* in_sizes, int n_in,
                              void* d_out, int out_size, void* d_ws, size_t ws_size,
                              hipStream_t stream)
{
    const float* u  = (const float*)d_in[0];
    const float* W1 = (const float*)d_in[1];
    const float* b1 = (const float*)d_in[2];
    const float* W2 = (const float*)d_in[3];
    const float* b2 = (const float*)d_in[4];
    const float* W3 = (const float*)d_in[5];
    const float* b3 = (const float*)d_in[6];
    const float* W4 = (const float*)d_in[7];
    // d_in[8] = b4: unused (bias does not enter the Jacobian)
    float* out = (float*)d_out;
    unsigned char* wsb = (unsigned char*)d_ws;   // needs 210176 B

    const int B = in_sizes[0] / 4;
    hipLaunchKernelGGL(conv_w_kernel, dim3((16384 + 2048 + 512 + 255) / 256), dim3(256), 0, stream,
                       W1, W2, W3, W4, wsb);
    const int nblocks = (B + 63) / 64;
    hipLaunchKernelGGL(wnn_jac_kernel, dim3(nblocks), dim3(256), 0, stream,
                       u, W1, b1, b2, b3, wsb, out, B);
}

// Round 23
// 212.472 us; speedup vs baseline: 1.1417x; 1.1417x over previous
//
#include <hip/hip_runtime.h>

#define HIDN 128
#define VSTR 272           // LDS V-buffer row stride BYTES (17x16B -> conflict-free b128)
#define ASTR 132           // f32 activation row stride (floats)

// d_ws byte offsets. Forward weights TRANSPOSED: WT[jc][unit][4kk] f32, row
// stride 2064B (non-pow2 — R14). Per jc the 32 needed units are 512B contiguous.
#define WSB_W2T 0                    // f32 [32][128][4], rows 2064B
#define WSB_W3T 66048
#define WSB_W2B 135168               // bf16 [128] rows, stride 272B (tangent)
#define WSB_W3B 169984
#define WSB_W4B 204800               // bf16 [16] rows, stride 272B (rows 4..15 zero)
#define WSB_W1T 209152               // bf16 [4][128] contiguous
#define WSB_TOT 210176

typedef __attribute__((ext_vector_type(8))) short short8;
typedef __attribute__((ext_vector_type(4))) float f32x4;

// Paired-row bf16 W load: 8 loads + wait in ONE self-contained asm block
// (R13-proven; multi-block register pipelines/hoists spill — R16/R22, 4-for-4).
#define LOAD_A8(dst, b0, b1)                                                  \
    asm volatile("global_load_dwordx4 %0, %8, off\n\t"                        \
                 "global_load_dwordx4 %1, %8, off offset:64\n\t"              \
                 "global_load_dwordx4 %2, %8, off offset:128\n\t"             \
                 "global_load_dwordx4 %3, %8, off offset:192\n\t"             \
                 "global_load_dwordx4 %4, %9, off\n\t"                        \
                 "global_load_dwordx4 %5, %9, off offset:64\n\t"              \
                 "global_load_dwordx4 %6, %9, off offset:128\n\t"             \
                 "global_load_dwordx4 %7, %9, off offset:192\n\t"             \
                 "s_waitcnt vmcnt(0)"                                         \
                 : "=&v"(dst[0]), "=&v"(dst[1]), "=&v"(dst[2]), "=&v"(dst[3]),\
                   "=&v"(dst[4]), "=&v"(dst[5]), "=&v"(dst[6]), "=&v"(dst[7]) \
                 : "v"(b0), "v"(b1)                                           \
                 : "memory")

// f32 -> bf16 round-to-nearest-even
__device__ __forceinline__ unsigned short f2bf(float f) {
    unsigned b = __float_as_uint(f);
    b += 0x7FFFu + ((b >> 16) & 1u);
    return (unsigned short)(b >> 16);
}

// ---------- prelude: one-time weight repack into ws ----------
__global__ void conv_w_kernel(const float* __restrict__ W1, const float* __restrict__ W2,
                              const float* __restrict__ W3, const float* __restrict__ W4,
                              unsigned char* __restrict__ ws)
{
    const int idx = blockIdx.x * 256 + threadIdx.x;
    if (idx < 16384) {
        const int r = idx >> 7, c = idx & 127;           // unit r, k-col c
        const int jc = c >> 2, kk = c & 3;
        *(float*)(ws + WSB_W2T + jc * 2064 + r * 16 + kk * 4) = W2[idx];   // f32 verbatim
        *(float*)(ws + WSB_W3T + jc * 2064 + r * 16 + kk * 4) = W3[idx];
        *(unsigned short*)(ws + WSB_W2B + r * 272 + c * 2) = f2bf(W2[idx]);
        *(unsigned short*)(ws + WSB_W3B + r * 272 + c * 2) = f2bf(W3[idx]);
    } else if (idx < 16384 + 2048) {
        const int t = idx - 16384;
        const int r = t >> 7, c = t & 127;
        *(unsigned short*)(ws + WSB_W4B + r * 272 + c * 2) =
            (r < 4) ? f2bf(W4[r * HIDN + c]) : (unsigned short)0;
    } else if (idx < 16384 + 2048 + 512) {
        const int t = idx - 16384 - 2048;
        const int cc = t >> 7, j = t & 127;
        *(unsigned short*)(ws + WSB_W1T + cc * 256 + j * 2) = f2bf(W1[j * 4 + cc]);
    }
}

// One tangent layer, WIDE split (R21-proven): wave owns UNITS [ub, ub+32) for
// ALL 64 sc-rows. W fragments = ONE LOAD_A8 per layer call (L2-hot reload each
// subtile — cheaper than register hoisting, which spills: R22).
// PING-PONG src != dst (in-place corrupts — R6/R8). msk = SUBTILE SAMPLE BASE.
__device__ __forceinline__ void tangent_layer_wide(const unsigned char* __restrict__ src,
                                                   unsigned char* __restrict__ dst,
                                                   const unsigned char* __restrict__ Wb,  // 272B rows
                                                   const unsigned char* __restrict__ msk, // [16][16]
                                                   int ub, int lr, int lk)
{
    short8 aw[8];   // 2 ib-blocks x 4 k-slices
    LOAD_A8(aw, Wb + (ub + lr) * 272 + lk * 16,
                Wb + (ub + 16 + lr) * 272 + lk * 16);
    const int ib0 = ub >> 4;
    #pragma unroll
    for (int q = 0; q < 4; ++q) {
        const int sc = q * 16 + lr;
        short8 b[4];
        #pragma unroll
        for (int ks = 0; ks < 4; ++ks)
            b[ks] = *(const short8*)(src + sc * VSTR + ks * 64 + lk * 16);
        #pragma unroll
        for (int h = 0; h < 2; ++h) {
            const int ib = ib0 + h;
            f32x4 c = (f32x4){0.f, 0.f, 0.f, 0.f};
            #pragma unroll
            for (int ks = 0; ks < 4; ++ks)
                c = __builtin_amdgcn_mfma_f32_16x16x32_bf16(aw[h * 4 + ks], b[ks], c, 0, 0, 0);
            const unsigned bits = (msk[(sc >> 2) * 16 + ib * 2 + (lk >> 1)] >> ((lk & 1) * 4)) & 0xFu;
            unsigned long long pk = 0;
            #pragma unroll
            for (int r = 0; r < 4; ++r) {
                const unsigned short v = ((bits >> r) & 1u) ? f2bf(c[r]) : (unsigned short)0;
                pk |= (unsigned long long)v << (r * 16);
            }
            *(unsigned long long*)(dst + sc * VSTR + (ib * 16 + lk * 4) * 2) = pk;
        }
    }
}

__global__ __launch_bounds__(256, 4)
void wnn_jac_kernel(const float* __restrict__ u,
                    const float* __restrict__ W1, const float* __restrict__ b1,
                    const float* __restrict__ b2, const float* __restrict__ b3,
                    const unsigned char* __restrict__ wsb,
                    float* __restrict__ out, int Btot)
{
    // [0,17408) vA ; [17408,34816) vB ; forward aliases [0,33792) as f32 abuf[64][132]
    __shared__ __align__(16) unsigned char smem[34816];
    __shared__ unsigned char mlds8[3][64][16];   // [layer][sample][unit>>3] (3072 B)
    __shared__ float jbuf[64 * 5];               // [sc][c'] stride 5 (1280 B)

    unsigned char* vA = smem;
    unsigned char* vB = smem + 17408;
    float* abuf = (float*)smem;

    const int tid  = threadIdx.x;
    const long sg0 = (long)blockIdx.x * 64;

    // ================== FORWARD: lane = sample, wave = unit-quarter (uniform W) — R20 verbatim ==================
    {
        const int ls = tid & 63;                                   // sample
        const int wq = __builtin_amdgcn_readfirstlane(tid >> 6);   // uniform quarter 0..3
        const int i0 = wq * 32;
        const bool valid = (sg0 + ls < (long)Btot);

        float4 uv = make_float4(0.f, 0.f, 0.f, 0.f);
        if (valid) uv = *(const float4*)(u + (sg0 + ls) * 4);

        // ---- layer 1: 32 units/wave (uniform W1 rows), bit-exact chain, bias after ----
        {
            unsigned m = 0;
            #pragma unroll
            for (int ii = 0; ii < 32; ++ii) {
                const int i = i0 + ii;
                const float4 w = *(const float4*)(W1 + i * 4);     // uniform
                float h = 0.f;
                h = fmaf(w.x, uv.x, h);
                h = fmaf(w.y, uv.y, h);
                h = fmaf(w.z, uv.z, h);
                h = fmaf(w.w, uv.w, h);
                h = h + b1[i];
                if (h > 0.f) m |= (1u << ii);
                abuf[ls * ASTR + i] = fmaxf(h, 0.f);
            }
            *(unsigned*)&mlds8[0][ls][wq * 4] = m;
        }
        __syncthreads();   // B1: a1 complete

        // ---- layer 2: jc-OUTER / all-32-units-INNER (R20-proven) ----
        float acc2[32];
        {
            #pragma unroll
            for (int ii = 0; ii < 32; ++ii) acc2[ii] = 0.f;
            #pragma unroll 8
            for (int jc = 0; jc < 32; ++jc) {
                const f32x4 av = *(const f32x4*)(abuf + ls * ASTR + jc * 4);
                const float* wt = (const float*)(wsb + WSB_W2T + jc * 2064 + i0 * 16); // uniform 512B
                #pragma unroll
                for (int ii = 0; ii < 32; ++ii) {
                    const float* wr = wt + ii * 4;
                    float a = acc2[ii];
                    a = fmaf(wr[0], av[0], a);
                    a = fmaf(wr[1], av[1], a);
                    a = fmaf(wr[2], av[2], a);
                    a = fmaf(wr[3], av[3], a);
                    acc2[ii] = a;
                }
            }
        }
        __syncthreads();   // B2: ALL a1 reads complete -> safe to overwrite abuf with a2
        {
            unsigned m = 0;
            #pragma unroll
            for (int ii = 0; ii < 32; ++ii) {
                const float h = acc2[ii] + b2[i0 + ii];
                if (h > 0.f) m |= (1u << ii);
                abuf[ls * ASTR + i0 + ii] = fmaxf(h, 0.f);
            }
            *(unsigned*)&mlds8[1][ls][wq * 4] = m;
        }
        __syncthreads();   // B3: a2 complete

        // ---- layer 3 (mask only), same jc-outer structure ----
        {
            #pragma unroll
            for (int ii = 0; ii < 32; ++ii) acc2[ii] = 0.f;
            #pragma unroll 8
            for (int jc = 0; jc < 32; ++jc) {
                const f32x4 av = *(const f32x4*)(abuf + ls * ASTR + jc * 4);
                const float* wt = (const float*)(wsb + WSB_W3T + jc * 2064 + i0 * 16); // uniform 512B
                #pragma unroll
                for (int ii = 0; ii < 32; ++ii) {
                    const float* wr = wt + ii * 4;
                    float a = acc2[ii];
                    a = fmaf(wr[0], av[0], a);
                    a = fmaf(wr[1], av[1], a);
                    a = fmaf(wr[2], av[2], a);
                    a = fmaf(wr[3], av[3], a);
                    acc2[ii] = a;
                }
            }
            unsigned m = 0;
            #pragma unroll
            for (int ii = 0; ii < 32; ++ii) {
                const float h = acc2[ii] + b3[i0 + ii];
                if (h > 0.f) m |= (1u << ii);
            }
            *(unsigned*)&mlds8[2][ls][wq * 4] = m;
        }
    }
    __syncthreads();   // B4: masks visible; abuf dead -> vA/vB reusable

    // ================== TANGENT: 4 subtiles, wide unit-split (R21) ==================
    const unsigned char* ml8 = &mlds8[0][0][0];
    const int lane = tid & 63, wv = tid >> 6;
    const int lr = lane & 15, lk = lane >> 4;
    const int ub = wv * 32;    // this wave's unit base for tangent layers

    // W4 fragments are subtile-invariant: load ONCE (16 VGPR — proven safe in R21;
    // hoisting MORE than this spills, R22).
    short8 a4f[4];
    #pragma unroll
    for (int ks = 0; ks < 4; ++ks)
        a4f[ks] = *(const short8*)(wsb + WSB_W4B + lr * 272 + ks * 64 + lk * 16);

    #pragma unroll 1
    for (int st = 0; st < 4; ++st) {
        __syncthreads();   // prev subtile's vA readers (Jf/L3 writers) done -> v1 may overwrite

        // ---- v1 build: vA rows [wv*16, wv*16+16) = bf16(m1 .* W1 cols) ----
        {
            const int row = wv * 16 + (lane >> 2), kq = lane & 3;
            const int vs = (lane >> 4), vc = (lane >> 2) & 3;
            const unsigned char* mrec = ml8 + (0 * 64 + st * 16 + wv * 4 + vs) * 16;
            const unsigned short* w1t = (const unsigned short*)(wsb + WSB_W1T) + vc * HIDN;
            #pragma unroll
            for (int t = 0; t < 4; ++t) {
                const int j0 = kq * 32 + t * 8;
                const short8 w = *(const short8*)(w1t + j0);
                short8 fr;
                #pragma unroll
                for (int e = 0; e < 8; ++e) {
                    const int j = j0 + e;
                    fr[e] = ((mrec[j >> 3] >> (j & 7)) & 1u) ? w[e] : (short)0;
                }
                *(short8*)(vA + row * VSTR + j0 * 2) = fr;
            }
        }
        __syncthreads();   // all vA rows ready (L2 reads every row)

        // ---- tangent L2: vA -> vB (wave computes its 32 units for all 64 rows) ----
        tangent_layer_wide(vA, vB, wsb + WSB_W2B, ml8 + (1 * 64 + st * 16) * 16, ub, lr, lk);
        __syncthreads();   // all vB writes visible

        // ---- tangent L3: vB -> vA ----
        tangent_layer_wide(vB, vA, wsb + WSB_W3B, ml8 + (2 * 64 + st * 16) * 16, ub, lr, lk);
        __syncthreads();   // all vA writes visible (Jf reads full rows)

        // ---- Jf: D[c'][sc] = sum_j W4[c'][j] * V3[sc][j] (own wave's 16 rows) ----
        {
            short8 b[4];
            #pragma unroll
            for (int ks = 0; ks < 4; ++ks)
                b[ks] = *(const short8*)(vA + (wv * 16 + lr) * VSTR + ks * 64 + lk * 16);
            f32x4 c = (f32x4){0.f, 0.f, 0.f, 0.f};
            #pragma unroll
            for (int ks = 0; ks < 4; ++ks)
                c = __builtin_amdgcn_mfma_f32_16x16x32_bf16(a4f[ks], b[ks], c, 0, 0, 0);
            if (lk == 0) {   // c' = r (0..3); sc = wv*16+lr -> jbuf rows wave-private
                const int sc = wv * 16 + lr;
                #pragma unroll
                for (int r = 0; r < 4; ++r)
                    jbuf[sc * 5 + r] = c[r];
            }
        }
        // wave-internal jbuf handoff: both sides are LDS ops -> "memory" clobber orders them
        asm volatile("s_waitcnt lgkmcnt(0)" ::: "memory");
        __builtin_amdgcn_sched_barrier(0);

        // ---- per-wave epilogue (lanes 0-15): samples wv*4 .. wv*4+3 of this subtile ----
        if (lk == 0) {
            const int es = lr >> 2, ea = lr & 3;
            const long sg = sg0 + st * 16 + wv * 4 + es;
            if (sg < (long)Btot) {
                const float* jb = jbuf + (wv * 16 + es * 4) * 5;
                float4 o;
                o.x = jb[ea * 5 + 0] - jb[0 * 5 + ea];
                o.y = jb[ea * 5 + 1] - jb[1 * 5 + ea];
                o.z = jb[ea * 5 + 2] - jb[2 * 5 + ea];
                o.w = jb[ea * 5 + 3] - jb[3 * 5 + ea];
                *(float4*)(out + sg * 16 + ea * 4) = o;
            }
        }
    }
}

extern "C" void kernel_launch(void* const* d_in, const int* in_sizes, int n_in,
                              void* d_out, int out_size, void* d_ws, size_t ws_size,
                              hipStream_t stream)
{
    const float* u  = (const float*)d_in[0];
    const float* W1 = (const float*)d_in[1];
    const float* b1 = (const float*)d_in[2];
    const float* W2 = (const float*)d_in[3];
    const float* b2 = (const float*)d_in[4];
    const float* W3 = (const float*)d_in[5];
    const float* b3 = (const float*)d_in[6];
    const float* W4 = (const float*)d_in[7];
    // d_in[8] = b4: unused (bias does not enter the Jacobian)
    float* out = (float*)d_out;
    unsigned char* wsb = (unsigned char*)d_ws;   // needs 210176 B

    const int B = in_sizes[0] / 4;
    hipLaunchKernelGGL(conv_w_kernel, dim3((16384 + 2048 + 512 + 255) / 256), dim3(256), 0, stream,
                       W1, W2, W3, W4, wsb);
    const int nblocks = (B + 63) / 64;
    hipLaunchKernelGGL(wnn_jac_kernel, dim3(nblocks), dim3(256), 0, stream,
                       u, W1, b1, b2, b3, wsb, out, B);
}